// Round 3
// baseline (261.361 us; speedup 1.0000x reference)
//
#include <hip/hip_runtime.h>

typedef __attribute__((ext_vector_type(8))) short short8;
typedef __attribute__((ext_vector_type(4))) float f32x4;
typedef __attribute__((ext_vector_type(4))) int i32x4;

#define NSEQ 4096
#define MSEQ 1024
#define HID  512
#define CTXD 768

static __device__ __forceinline__ unsigned short f2bf(float f) {
  union { float f; unsigned u; } v; v.f = f;
  return (unsigned short)((v.u + 0x7fffu + ((v.u >> 16) & 1u)) >> 16);
}

static __device__ __forceinline__ void gld16(const void* g, void* l) {
  __builtin_amdgcn_global_load_lds((const __attribute__((address_space(1))) void*)g,
                                   (__attribute__((address_space(3))) void*)l, 16, 0, 0);
}
static __device__ __forceinline__ void gld4(const void* g, void* l) {
  __builtin_amdgcn_global_load_lds((const __attribute__((address_space(1))) void*)g,
                                   (__attribute__((address_space(3))) void*)l, 4, 0, 0);
}

// ---------------- weight transpose: W[K][N] f32 -> WT[N][K] bf16 ----------------
__global__ void k_transpose(const float* __restrict__ W, unsigned short* __restrict__ WT,
                            int K, int N) {
  __shared__ float tile[32][33];
  int k0 = blockIdx.x * 32, n0 = blockIdx.y * 32;
  int tx = threadIdx.x, ty = threadIdx.y;
#pragma unroll
  for (int i = 0; i < 32; i += 8)
    tile[ty + i][tx] = W[(size_t)(k0 + ty + i) * N + n0 + tx];
  __syncthreads();
#pragma unroll
  for (int i = 0; i < 32; i += 8)
    WT[(size_t)(n0 + ty + i) * K + k0 + tx] = f2bf(tile[tx][ty + i]);
}

// ---------------- f32 -> bf16 cast, vectorized ----------------
__global__ void k_cast(const float* __restrict__ in, unsigned short* __restrict__ out, int n8) {
  int i = blockIdx.x * blockDim.x + threadIdx.x;
  int stride = gridDim.x * blockDim.x;
  for (; i < n8; i += stride) {
    f32x4 v0 = *(const f32x4*)(in + (size_t)i * 8);
    f32x4 v1 = *(const f32x4*)(in + (size_t)i * 8 + 4);
    unsigned short tmp[8] __attribute__((aligned(16)));
    tmp[0] = f2bf(v0[0]); tmp[1] = f2bf(v0[1]); tmp[2] = f2bf(v0[2]); tmp[3] = f2bf(v0[3]);
    tmp[4] = f2bf(v1[0]); tmp[5] = f2bf(v1[1]); tmp[6] = f2bf(v1[2]); tmp[7] = f2bf(v1[3]);
    *(i32x4*)(out + (size_t)i * 8) = *(const i32x4*)tmp;
  }
}

// ---------------- GEMM: C[M][N] = A[M][K](bf16) * BT[N][K](bf16)^T ----------------
// 128x128 tile, BK=64, 4 waves (2x2). global_load_lds staging (linear LDS dest,
// inverse-swizzled global source), double-buffered, counted vmcnt, raw s_barrier.
// BIAS_MODE: 0 none, 1 per-col, 2 per-row.
template<int BIAS_MODE, bool RES, bool OUT_BF16>
__global__ __launch_bounds__(256, 2) void k_gemm(
    const unsigned short* __restrict__ A, const unsigned short* __restrict__ B,
    const float* __restrict__ bias, const float* __restrict__ resv,
    void* __restrict__ Cv, int M, int N, int K,
    long sA, long sB, long sC, long sR) {
  __shared__ __align__(16) char lds[65536];  // 2 bufs x (A 16K + B 16K)
  const int t = threadIdx.x, lane = t & 63, wid = t >> 6;
  const int wr = wid >> 1, wc = wid & 1;
  const int m0 = blockIdx.x * 128, n0 = blockIdx.y * 128, z = blockIdx.z;
  const unsigned short* Ab = A + (size_t)z * sA;
  const unsigned short* Bb = B + (size_t)z * sB;

  const f32x4 fz = {0.f, 0.f, 0.f, 0.f};
  f32x4 acc[4][4];
#pragma unroll
  for (int i = 0; i < 4; i++)
#pragma unroll
    for (int j = 0; j < 4; j++) acc[i][j] = fz;

  const int srow = t >> 3;      // 0..31 (+32 per issue)
  const int schunk = t & 7;

  auto stage = [&](int kk, int buf) {
    const char* a8 = (const char*)Ab;
    const char* b8 = (const char*)Bb;
#pragma unroll
    for (int i = 0; i < 4; i++) {
      int row = i * 32 + srow;
      gld16(a8 + ((size_t)(m0 + row) * K + kk) * 2 + ((schunk ^ (row & 7)) << 4),
            lds + buf * 32768 + i * 4096 + wid * 1024);
    }
#pragma unroll
    for (int i = 0; i < 4; i++) {
      int row = i * 32 + srow;
      gld16(b8 + ((size_t)(n0 + row) * K + kk) * 2 + ((schunk ^ (row & 7)) << 4),
            lds + buf * 32768 + 16384 + i * 4096 + wid * 1024);
    }
  };

  stage(0, 0);
  int buf = 0;
  for (int kk = 0; kk < K; kk += 64) {
    if (kk + 64 < K) {
      stage(kk + 64, buf ^ 1);
      asm volatile("s_waitcnt vmcnt(8)" ::: "memory");
    } else {
      asm volatile("s_waitcnt vmcnt(0)" ::: "memory");
    }
    __builtin_amdgcn_s_barrier();
    const char* As = lds + buf * 32768;
    const char* Bs = As + 16384;
#pragma unroll
    for (int ks = 0; ks < 2; ks++) {
      short8 af[4], bfr[4];
#pragma unroll
      for (int i = 0; i < 4; i++) {
        int r = wr * 64 + i * 16 + (lane & 15);
        af[i] = *(const short8*)(As + r * 128 +
                 (((unsigned)(ks * 64 + (lane >> 4) * 16)) ^ ((unsigned)(r & 7) << 4)));
      }
#pragma unroll
      for (int i = 0; i < 4; i++) {
        int r = wc * 64 + i * 16 + (lane & 15);
        bfr[i] = *(const short8*)(Bs + r * 128 +
                 (((unsigned)(ks * 64 + (lane >> 4) * 16)) ^ ((unsigned)(r & 7) << 4)));
      }
#pragma unroll
      for (int i = 0; i < 4; i++)
#pragma unroll
        for (int j = 0; j < 4; j++)
          acc[i][j] = __builtin_amdgcn_mfma_f32_16x16x32_bf16(af[i], bfr[j], acc[i][j], 0, 0, 0);
    }
    asm volatile("s_waitcnt lgkmcnt(0)" ::: "memory");
    __builtin_amdgcn_s_barrier();
    buf ^= 1;
  }

  const float* res = RES ? (resv + (size_t)z * sR) : nullptr;
  char* Cb = (char*)Cv + (size_t)z * sC * (OUT_BF16 ? 2 : 4);
#pragma unroll
  for (int i = 0; i < 4; i++) {
#pragma unroll
    for (int jj = 0; jj < 4; jj++) {
      int row = m0 + wr * 64 + i * 16 + (lane >> 4) * 4 + jj;
#pragma unroll
      for (int j = 0; j < 4; j++) {
        int col = n0 + wc * 64 + j * 16 + (lane & 15);
        float v = acc[i][j][jj];
        if (BIAS_MODE == 1) v += bias[col];
        if (BIAS_MODE == 2) v += bias[row];
        if (RES) v += res[(size_t)row * N + col];
        if (OUT_BF16) ((unsigned short*)Cb)[(size_t)row * N + col] = f2bf(v);
        else          ((float*)Cb)[(size_t)row * N + col] = v;
      }
    }
  }
}

// ---------------- fused attention: softmax(q k^T * scale) @ v ----------------
// Block: 64 q-rows x full M=1024, 8 waves, 1 block/CU.
// Phase A (QK^T): wave w owns m-slice [w*128,+128); S (64x1024 f32) in regs
//   (128 VGPR/lane); K streamed [1024][32-hid] 64KB chunks + Q [64][32] 4KB,
//   double-buffered global_load_lds, counted vmcnt.
// Phase B: exact softmax, normalize in regs, P^ (bf16) -> LDS [64][1024]
//   swizzled (overlays dead K buffers, 128KB).
// Phase C (PV): wave w owns e-slice [w*64,+64); A=P^ rows from LDS,
//   B=V^T rows direct from L2 (4-deep reg pipeline); O -> LDS -> coalesced store.
__global__ __launch_bounds__(512, 1) void k_attn(
    const unsigned short* __restrict__ qb,   // [B*4096][512] bf16
    const unsigned short* __restrict__ kb,   // [B*1024][512] bf16
    const unsigned short* __restrict__ vT,   // [B][512][1024] bf16 (V^T)
    unsigned short* __restrict__ ctxb) {     // [B*4096][512] bf16
  __shared__ __align__(16) char lds[143616];
  char* Kb0 = lds;                         // [2][65536]   (phase A)
  char* Ps  = lds;                         // [64][2048B] swizzled P^ (phase B/C)
  char* Ob  = lds;                         // [64][1024B] swizzled O  (epilogue)
  char* Qb0 = lds + 131072;                // [2][4096]
  float* pmax = (float*)(lds + 139264);    // [8][64]
  float* psum = (float*)(lds + 141312);    // [8][64]
  float* gbuf = (float*)(lds + 143360);    // [64]

  const int t = threadIdx.x, lane = t & 63, w = t >> 6;
  const int g = lane >> 4, l15 = lane & 15;
  const int bid = blockIdx.x;
  const int b = bid & 7;                   // batch -> XCD affinity
  const int n0 = (bid >> 3) * 64;
  const char* qbase = (const char*)(qb + ((size_t)b * NSEQ + n0) * HID);
  const char* kbase = (const char*)(kb + (size_t)b * MSEQ * HID);

  auto stage = [&](int ks2, int buf) {
#pragma unroll
    for (int i = 0; i < 8; i++) {
      int row = i * 128 + (t >> 2);
      int c = t & 3;
      gld16(kbase + ((size_t)row * HID + ks2 * 32) * 2 + ((c ^ ((row >> 1) & 3)) << 4),
            Kb0 + buf * 65536 + i * 8192 + w * 1024);
    }
#pragma unroll
    for (int j = 0; j < 2; j++) {
      int row = j * 32 + (t >> 4);
      int o = (t & 15) * 4;
      gld4(qbase + ((size_t)row * HID + ks2 * 32) * 2 +
               ((((o >> 4) ^ ((row >> 1) & 3)) << 4) | (o & 15)),
           Qb0 + buf * 4096 + j * 2048 + w * 256);
    }
  };

  const f32x4 fz = {0.f, 0.f, 0.f, 0.f};
  f32x4 s[4][8];
#pragma unroll
  for (int qf = 0; qf < 4; qf++)
#pragma unroll
    for (int mf = 0; mf < 8; mf++) s[qf][mf] = fz;

  // ---- phase A: QK^T ----
  stage(0, 0);
  int buf = 0;
  for (int ks2 = 0; ks2 < 16; ks2++) {
    if (ks2 < 15) {
      stage(ks2 + 1, buf ^ 1);
      asm volatile("s_waitcnt vmcnt(10)" ::: "memory");
    } else {
      asm volatile("s_waitcnt vmcnt(0)" ::: "memory");
    }
    __builtin_amdgcn_s_barrier();
    const char* Kc = Kb0 + buf * 65536;
    const char* Qc = Qb0 + buf * 4096;
    short8 aq[4], bk[8];
#pragma unroll
    for (int qf = 0; qf < 4; qf++) {
      int q = qf * 16 + l15;
      aq[qf] = *(const short8*)(Qc + q * 64 + ((g * 16) ^ (((q >> 1) & 3) << 4)));
    }
#pragma unroll
    for (int mf = 0; mf < 8; mf++) {
      int m = w * 128 + mf * 16 + l15;
      bk[mf] = *(const short8*)(Kc + m * 64 + ((g * 16) ^ (((m >> 1) & 3) << 4)));
    }
#pragma unroll
    for (int qf = 0; qf < 4; qf++)
#pragma unroll
      for (int mf = 0; mf < 8; mf++)
        s[qf][mf] = __builtin_amdgcn_mfma_f32_16x16x32_bf16(aq[qf], bk[mf], s[qf][mf], 0, 0, 0);
    asm volatile("s_waitcnt lgkmcnt(0)" ::: "memory");
    __builtin_amdgcn_s_barrier();
    buf ^= 1;
  }

  // ---- phase B: softmax (exact, full row) ----
  const float scale = 0.044194173824159216f;  // 512^-0.5
#pragma unroll
  for (int qf = 0; qf < 4; qf++)
#pragma unroll
    for (int mf = 0; mf < 8; mf++)
#pragma unroll
      for (int jj = 0; jj < 4; jj++) s[qf][mf][jj] *= scale;

  float rmax[4][4];
#pragma unroll
  for (int qf = 0; qf < 4; qf++)
#pragma unroll
    for (int jj = 0; jj < 4; jj++) {
      float m = s[qf][0][jj];
#pragma unroll
      for (int mf = 1; mf < 8; mf++) m = fmaxf(m, s[qf][mf][jj]);
      rmax[qf][jj] = m;
    }
#pragma unroll
  for (int d = 1; d < 16; d <<= 1)
#pragma unroll
    for (int qf = 0; qf < 4; qf++)
#pragma unroll
      for (int jj = 0; jj < 4; jj++)
        rmax[qf][jj] = fmaxf(rmax[qf][jj], __shfl_xor(rmax[qf][jj], d, 64));
  if (l15 == 0) {
#pragma unroll
    for (int qf = 0; qf < 4; qf++)
#pragma unroll
      for (int jj = 0; jj < 4; jj++)
        pmax[w * 64 + qf * 16 + g * 4 + jj] = rmax[qf][jj];
  }
  __syncthreads();
  if (t < 64) {
    float m = pmax[t];
#pragma unroll
    for (int ww = 1; ww < 8; ww++) m = fmaxf(m, pmax[ww * 64 + t]);
    gbuf[t] = m;
  }
  __syncthreads();
  float fm[4][4], rs[4][4];
#pragma unroll
  for (int qf = 0; qf < 4; qf++)
#pragma unroll
    for (int jj = 0; jj < 4; jj++) {
      fm[qf][jj] = gbuf[qf * 16 + g * 4 + jj];
      rs[qf][jj] = 0.f;
    }
#pragma unroll
  for (int qf = 0; qf < 4; qf++)
#pragma unroll
    for (int mf = 0; mf < 8; mf++)
#pragma unroll
      for (int jj = 0; jj < 4; jj++) {
        float p = __expf(s[qf][mf][jj] - fm[qf][jj]);
        s[qf][mf][jj] = p;
        rs[qf][jj] += p;
      }
#pragma unroll
  for (int d = 1; d < 16; d <<= 1)
#pragma unroll
    for (int qf = 0; qf < 4; qf++)
#pragma unroll
      for (int jj = 0; jj < 4; jj++)
        rs[qf][jj] += __shfl_xor(rs[qf][jj], d, 64);
  __syncthreads();
  if (l15 == 0) {
#pragma unroll
    for (int qf = 0; qf < 4; qf++)
#pragma unroll
      for (int jj = 0; jj < 4; jj++)
        psum[w * 64 + qf * 16 + g * 4 + jj] = rs[qf][jj];
  }
  __syncthreads();
  if (t < 64) {
    float ssum = psum[t];
#pragma unroll
    for (int ww = 1; ww < 8; ww++) ssum += psum[ww * 64 + t];
    gbuf[t] = 1.0f / ssum;
  }
  __syncthreads();   // gbuf ready; K/Q buffers dead -> safe to write P^ over them

  // ---- P^ (normalized, bf16) -> LDS [64 rows][2048B], XOR swizzle (row&15)<<4
#pragma unroll
  for (int qf = 0; qf < 4; qf++)
#pragma unroll
    for (int jj = 0; jj < 4; jj++) {
      int row = qf * 16 + g * 4 + jj;
      float fi = gbuf[row];
      char* pr = Ps + row * 2048;
      unsigned sw = (unsigned)(row & 15) << 4;
#pragma unroll
      for (int mf = 0; mf < 8; mf++) {
        int m = w * 128 + mf * 16 + l15;
        *(unsigned short*)(pr + (((unsigned)(m * 2)) ^ sw)) = f2bf(s[qf][mf][jj] * fi);
      }
    }
  __syncthreads();

  // ---- phase C: O[64q][e-slice 64] = P^ @ V  (wave w: e in [w*64,+64))
  const unsigned short* vbase = vT + (size_t)b * HID * MSEQ;
  const int e00 = w * 64;
  f32x4 o[4][4];
#pragma unroll
  for (int qf = 0; qf < 4; qf++)
#pragma unroll
    for (int ef = 0; ef < 4; ef++) o[qf][ef] = fz;

  auto ldb = [&](int ms, short8* dst) {
#pragma unroll
    for (int ef = 0; ef < 4; ef++)
      dst[ef] = *(const short8*)(vbase + (size_t)(e00 + ef * 16 + l15) * MSEQ + ms * 32 + g * 8);
  };
  auto step = [&](int ms, short8* vb) {
    short8 pa[4];
#pragma unroll
    for (int qf = 0; qf < 4; qf++) {
      int row = qf * 16 + l15;
      pa[qf] = *(const short8*)(Ps + row * 2048 +
               (((unsigned)(ms * 64 + g * 16)) ^ ((unsigned)(row & 15) << 4)));
    }
#pragma unroll
    for (int qf = 0; qf < 4; qf++)
#pragma unroll
      for (int ef = 0; ef < 4; ef++)
        o[qf][ef] = __builtin_amdgcn_mfma_f32_16x16x32_bf16(pa[qf], vb[ef], o[qf][ef], 0, 0, 0);
  };

  short8 vb0[4], vb1[4], vb2[4], vb3[4];
  ldb(0, vb0); ldb(1, vb1); ldb(2, vb2); ldb(3, vb3);
  for (int ms = 0; ms < 32; ms += 4) {
    step(ms + 0, vb0); if (ms + 4 < 32) ldb(ms + 4, vb0);
    step(ms + 1, vb1); if (ms + 5 < 32) ldb(ms + 5, vb1);
    step(ms + 2, vb2); if (ms + 6 < 32) ldb(ms + 6, vb2);
    step(ms + 3, vb3); if (ms + 7 < 32) ldb(ms + 7, vb3);
  }
  __syncthreads();   // all P^ reads done; safe to overwrite with O

  // ---- O -> LDS (bf16, swizzled) ----
#pragma unroll
  for (int qf = 0; qf < 4; qf++)
#pragma unroll
    for (int jj = 0; jj < 4; jj++) {
      int row = qf * 16 + g * 4 + jj;
      char* orow = Ob + row * 1024;
      unsigned sw = (unsigned)(row & 7) << 4;
#pragma unroll
      for (int ef = 0; ef < 4; ef++) {
        int e = e00 + ef * 16 + l15;
        *(unsigned short*)(orow + (((unsigned)(e * 2)) ^ sw)) = f2bf(o[qf][ef][jj]);
      }
    }
  __syncthreads();

  // ---- coalesced store: thread t -> row t>>3, 128B ----
  {
    unsigned short* cdst = ctxb + ((size_t)b * NSEQ + n0) * HID;
    int row = t >> 3, e0 = (t & 7) * 64;
    const char* orow = Ob + row * 1024;
    unsigned sw = (unsigned)(row & 7) << 4;
#pragma unroll
    for (int ch = 0; ch < 8; ch++) {
      i32x4 v = *(const i32x4*)(orow + (((unsigned)((e0 + ch * 8) * 2)) ^ sw));
      *(i32x4*)(cdst + (size_t)row * HID + e0 + ch * 8) = v;
    }
  }
}

// ---------------- launch ----------------
extern "C" void kernel_launch(void* const* d_in, const int* in_sizes, int n_in,
                              void* d_out, int out_size, void* d_ws, size_t ws_size,
                              hipStream_t stream) {
  (void)in_sizes; (void)n_in; (void)out_size; (void)ws_size;
  const float* x   = (const float*)d_in[0];
  const float* ctx = (const float*)d_in[1];
  const float* Wq  = (const float*)d_in[2];
  const float* bq  = (const float*)d_in[3];
  const float* Wk  = (const float*)d_in[4];
  const float* bk  = (const float*)d_in[5];
  const float* Wv  = (const float*)d_in[6];
  const float* bv  = (const float*)d_in[7];
  const float* Wo  = (const float*)d_in[8];
  const float* bo  = (const float*)d_in[9];
  float* out = (float*)d_out;

  char* ws = (char*)d_ws;
  unsigned short* qb   = (unsigned short*)(ws);              // 33,554,432
  unsigned short* kbuf = (unsigned short*)(ws + 33554432);   //  8,388,608
  unsigned short* vT   = (unsigned short*)(ws + 41943040);   //  8,388,608
  unsigned short* ctxb = (unsigned short*)(ws + 50331648);   // 33,554,432
  unsigned short* WqT  = (unsigned short*)(ws + 83886080);   //    524,288
  unsigned short* WkT  = (unsigned short*)(ws + 84410368);   //    786,432
  unsigned short* WvT  = (unsigned short*)(ws + 85196800);   //    786,432
  unsigned short* WoT  = (unsigned short*)(ws + 85983232);   //    524,288 -> 86,507,520
  unsigned short* xb   = (unsigned short*)(ws + 86507520);   // 33,554,432
  unsigned short* cb   = (unsigned short*)(ws + 120061952);  // 12,582,912 -> 132,644,864

  dim3 tb(32, 8);
  k_transpose<<<dim3(16, 16), tb, 0, stream>>>(Wq, WqT, 512, 512);
  k_transpose<<<dim3(24, 16), tb, 0, stream>>>(Wk, WkT, 768, 512);
  k_transpose<<<dim3(24, 16), tb, 0, stream>>>(Wv, WvT, 768, 512);
  k_transpose<<<dim3(16, 16), tb, 0, stream>>>(Wo, WoT, 512, 512);

  k_cast<<<dim3(2048), 256, 0, stream>>>(x,   xb, 2097152);  // 8*4096*512/8
  k_cast<<<dim3(2048), 256, 0, stream>>>(ctx, cb,  786432);  // 8*1024*768/8

  // q = x @ Wq + bq -> bf16 [32768][512]
  k_gemm<1, false, true><<<dim3(256, 4, 1), 256, 0, stream>>>(
      xb, WqT, bq, nullptr, qb, 32768, 512, 512, 0, 0, 0, 0);
  // k = ctx @ Wk + bk -> bf16 [8192][512]
  k_gemm<1, false, true><<<dim3(64, 4, 1), 256, 0, stream>>>(
      cb, WkT, bk, nullptr, kbuf, 8192, 512, 768, 0, 0, 0, 0);
  // vT[b] = (ctx[b] @ Wv + bv)^T -> bf16 [8][512][1024]
  k_gemm<2, false, true><<<dim3(4, 8, 8), 256, 0, stream>>>(
      WvT, cb, bv, nullptr, vT, 512, 1024, 768, 0, (long)1024 * 768, (long)512 * 1024, 0);
  // fused attention -> bf16 [32768][512]
  k_attn<<<dim3(512), 512, 0, stream>>>(qb, kbuf, vT, ctxb);
  // out = ctx_out @ Wo + bo + x -> f32
  k_gemm<1, true, false><<<dim3(256, 4, 1), 256, 0, stream>>>(
      ctxb, WoT, bo, x, out, 32768, 512, 512, 0, 0, 0, 0);
}

// Round 5
// 248.207 us; speedup vs baseline: 1.0530x; 1.0530x over previous
//
#include <hip/hip_runtime.h>

typedef __attribute__((ext_vector_type(8))) short short8;
typedef __attribute__((ext_vector_type(4))) float f32x4;
typedef __attribute__((ext_vector_type(4))) int i32x4;

#define NSEQ 4096
#define MSEQ 1024
#define HID  512
#define CTXD 768

static __device__ __forceinline__ unsigned short f2bf(float f) {
  union { float f; unsigned u; } v; v.f = f;
  return (unsigned short)((v.u + 0x7fffu + ((v.u >> 16) & 1u)) >> 16);
}
static __device__ __forceinline__ float bf2f(unsigned short u) {
  union { unsigned u; float f; } v; v.u = ((unsigned)u) << 16;
  return v.f;
}

static __device__ __forceinline__ void gld16(const void* g, void* l) {
  __builtin_amdgcn_global_load_lds((const __attribute__((address_space(1))) void*)g,
                                   (__attribute__((address_space(3))) void*)l, 16, 0, 0);
}

// ---------------- weight transpose: W[K][N] f32 -> WT[N][K] bf16 ----------------
__global__ void k_transpose(const float* __restrict__ W, unsigned short* __restrict__ WT,
                            int K, int N) {
  __shared__ float tile[32][33];
  int k0 = blockIdx.x * 32, n0 = blockIdx.y * 32;
  int tx = threadIdx.x, ty = threadIdx.y;
#pragma unroll
  for (int i = 0; i < 32; i += 8)
    tile[ty + i][tx] = W[(size_t)(k0 + ty + i) * N + n0 + tx];
  __syncthreads();
#pragma unroll
  for (int i = 0; i < 32; i += 8)
    WT[(size_t)(n0 + ty + i) * K + k0 + tx] = f2bf(tile[tx][ty + i]);
}

// ---------------- f32 -> bf16 cast, vectorized ----------------
__global__ void k_cast(const float* __restrict__ in, unsigned short* __restrict__ out, int n8) {
  int i = blockIdx.x * blockDim.x + threadIdx.x;
  int stride = gridDim.x * blockDim.x;
  for (; i < n8; i += stride) {
    f32x4 v0 = *(const f32x4*)(in + (size_t)i * 8);
    f32x4 v1 = *(const f32x4*)(in + (size_t)i * 8 + 4);
    unsigned short tmp[8] __attribute__((aligned(16)));
    tmp[0] = f2bf(v0[0]); tmp[1] = f2bf(v0[1]); tmp[2] = f2bf(v0[2]); tmp[3] = f2bf(v0[3]);
    tmp[4] = f2bf(v1[0]); tmp[5] = f2bf(v1[1]); tmp[6] = f2bf(v1[2]); tmp[7] = f2bf(v1[3]);
    *(i32x4*)(out + (size_t)i * 8) = *(const i32x4*)tmp;
  }
}

// ---------------- GEMM 128x128 (R2-proven): C = A[M][K] * BT[N][K]^T ------------
template<int BIAS_MODE, bool RES, bool OUT_BF16>
__global__ __launch_bounds__(256, 2) void k_gemm(
    const unsigned short* __restrict__ A, const unsigned short* __restrict__ B,
    const float* __restrict__ bias, const float* __restrict__ resv,
    void* __restrict__ Cv, int M, int N, int K,
    long sA, long sB, long sC, long sR) {
  __shared__ __align__(16) char lds[65536];
  const int t = threadIdx.x, lane = t & 63, wid = t >> 6;
  const int wr = wid >> 1, wc = wid & 1;
  const int m0 = blockIdx.x * 128, n0 = blockIdx.y * 128, z = blockIdx.z;
  const unsigned short* Ab = A + (size_t)z * sA;
  const unsigned short* Bb = B + (size_t)z * sB;

  const f32x4 fz = {0.f, 0.f, 0.f, 0.f};
  f32x4 acc[4][4];
#pragma unroll
  for (int i = 0; i < 4; i++)
#pragma unroll
    for (int j = 0; j < 4; j++) acc[i][j] = fz;

  const int srow = t >> 3;      // 0..31
  const int schunk = t & 7;

  auto stage = [&](int kk, int buf) {
    const char* a8 = (const char*)Ab;
    const char* b8 = (const char*)Bb;
#pragma unroll
    for (int i = 0; i < 4; i++) {
      int row = i * 32 + srow;
      gld16(a8 + ((size_t)(m0 + row) * K + kk) * 2 + ((schunk ^ (row & 7)) << 4),
            lds + buf * 32768 + i * 4096 + wid * 1024);
    }
#pragma unroll
    for (int i = 0; i < 4; i++) {
      int row = i * 32 + srow;
      gld16(b8 + ((size_t)(n0 + row) * K + kk) * 2 + ((schunk ^ (row & 7)) << 4),
            lds + buf * 32768 + 16384 + i * 4096 + wid * 1024);
    }
  };

  stage(0, 0);
  int buf = 0;
  for (int kk = 0; kk < K; kk += 64) {
    if (kk + 64 < K) {
      stage(kk + 64, buf ^ 1);
      asm volatile("s_waitcnt vmcnt(8)" ::: "memory");
    } else {
      asm volatile("s_waitcnt vmcnt(0)" ::: "memory");
    }
    __builtin_amdgcn_s_barrier();
    const char* As = lds + buf * 32768;
    const char* Bs = As + 16384;
#pragma unroll
    for (int ks = 0; ks < 2; ks++) {
      short8 af[4], bfr[4];
#pragma unroll
      for (int i = 0; i < 4; i++) {
        int r = wr * 64 + i * 16 + (lane & 15);
        af[i] = *(const short8*)(As + r * 128 +
                 (((unsigned)(ks * 64 + (lane >> 4) * 16)) ^ ((unsigned)(r & 7) << 4)));
      }
#pragma unroll
      for (int i = 0; i < 4; i++) {
        int r = wc * 64 + i * 16 + (lane & 15);
        bfr[i] = *(const short8*)(Bs + r * 128 +
                 (((unsigned)(ks * 64 + (lane >> 4) * 16)) ^ ((unsigned)(r & 7) << 4)));
      }
#pragma unroll
      for (int i = 0; i < 4; i++)
#pragma unroll
        for (int j = 0; j < 4; j++)
          acc[i][j] = __builtin_amdgcn_mfma_f32_16x16x32_bf16(af[i], bfr[j], acc[i][j], 0, 0, 0);
    }
    asm volatile("s_waitcnt lgkmcnt(0)" ::: "memory");
    __builtin_amdgcn_s_barrier();
    buf ^= 1;
  }

  const float* res = RES ? (resv + (size_t)z * sR) : nullptr;
  char* Cb = (char*)Cv + (size_t)z * sC * (OUT_BF16 ? 2 : 4);
#pragma unroll
  for (int i = 0; i < 4; i++) {
#pragma unroll
    for (int jj = 0; jj < 4; jj++) {
      int row = m0 + wr * 64 + i * 16 + (lane >> 4) * 4 + jj;
#pragma unroll
      for (int j = 0; j < 4; j++) {
        int col = n0 + wc * 64 + j * 16 + (lane & 15);
        float v = acc[i][j][jj];
        if (BIAS_MODE == 1) v += bias[col];
        if (BIAS_MODE == 2) v += bias[row];
        if (RES) v += res[(size_t)row * N + col];
        if (OUT_BF16) ((unsigned short*)Cb)[(size_t)row * N + col] = f2bf(v);
        else          ((float*)Cb)[(size_t)row * N + col] = v;
      }
    }
  }
}

// ---------------- GEMM 256x128, BK=64, 8 waves (2x4), 3-buffer ring ----------------
// Per K-tile: 4 phases {ds_read A-frags (+B at p0) | 2 global_load_lds | lgkmcnt(0)
// | setprio(1) 8 MFMA setprio(0) | s_barrier}. Prefetch distance 2 tiles, ring of 3
// LDS buffers, per-tile vmcnt(6) (6 loads/wave/tile) never drains mid-loop.
// Linear LDS dest (wave-uniform base) + inverse-swizzled global src + swizzled read.
template<int BIAS_MODE, bool RES, bool OUT_BF16>
__global__ __launch_bounds__(512, 1) void k_gemm2(
    const unsigned short* __restrict__ A, const unsigned short* __restrict__ B,
    const float* __restrict__ bias, const float* __restrict__ resv,
    void* __restrict__ Cv, int M, int N, int K,
    long sA, long sB, long sC, long sR) {
  __shared__ __align__(16) char lds[147456];   // 3 x (A 32K + B 16K)
  const int t = threadIdx.x, lane = t & 63, wid = t >> 6;
  const int wr = wid >> 2, wc = wid & 3;
  const int l15 = lane & 15, g = lane >> 4;
  const int m0 = blockIdx.x * 256, n0 = blockIdx.y * 128, z = blockIdx.z;
  const unsigned short* Ab = A + (size_t)z * sA;
  const unsigned short* Bb = B + (size_t)z * sB;

  const f32x4 fz = {0.f, 0.f, 0.f, 0.f};
  f32x4 acc[8][2];
#pragma unroll
  for (int i = 0; i < 8; i++) { acc[i][0] = fz; acc[i][1] = fz; }

  const int srow = t >> 3;      // wid*8 + (lane>>3)
  const int sc = t & 7;         // 16B chunk in 128B row

  // wave-uniform LDS dest (HW: base + lane*16); source row = u*64 + wid*8 + (lane>>3)
  auto stageA = [&](int kk, int buf, int u) {
    int row = u * 64 + srow;
    gld16((const char*)Ab + ((size_t)(m0 + row) * K + kk) * 2 + ((sc ^ (row & 7)) << 4),
          lds + buf * 49152 + u * 8192 + wid * 1024);
  };
  auto stageB = [&](int kk, int buf, int u) {
    int row = u * 64 + srow;
    gld16((const char*)Bb + ((size_t)(n0 + row) * K + kk) * 2 + ((sc ^ (row & 7)) << 4),
          lds + buf * 49152 + 32768 + u * 8192 + wid * 1024);
  };

  const int NT = K >> 6;
  // prologue: stage tiles 0 and 1
#pragma unroll
  for (int u = 0; u < 4; u++) stageA(0, 0, u);
#pragma unroll
  for (int u = 0; u < 2; u++) stageB(0, 0, u);
#pragma unroll
  for (int u = 0; u < 4; u++) stageA(64, 1, u);
#pragma unroll
  for (int u = 0; u < 2; u++) stageB(64, 1, u);

  const unsigned sws = (unsigned)(l15 & 7) << 4;
  for (int tt = 0; tt < NT; tt++) {
    if (tt + 1 < NT) { asm volatile("s_waitcnt vmcnt(6)" ::: "memory"); }
    else             { asm volatile("s_waitcnt vmcnt(0)" ::: "memory"); }
    __builtin_amdgcn_s_barrier();
    const char* As = lds + (tt % 3) * 49152;
    const char* Bs = As + 32768;
    const int kk2 = (tt + 2) << 6;
    const bool st = kk2 < K;
    const int bnext = (tt + 2) % 3;
    short8 bfr[2][2];
#pragma unroll
    for (int p = 0; p < 4; p++) {
      short8 af[2][2];
#pragma unroll
      for (int di = 0; di < 2; di++) {
        int r = wr * 128 + (p * 2 + di) * 16 + l15;
#pragma unroll
        for (int ks = 0; ks < 2; ks++)
          af[di][ks] = *(const short8*)(As + r * 128 + (((unsigned)(ks * 64 + g * 16)) ^ sws));
      }
      if (p == 0) {
#pragma unroll
        for (int j = 0; j < 2; j++) {
          int r = wc * 32 + j * 16 + l15;
#pragma unroll
          for (int ks = 0; ks < 2; ks++)
            bfr[j][ks] = *(const short8*)(Bs + r * 128 + (((unsigned)(ks * 64 + g * 16)) ^ sws));
        }
      }
      if (st) {
        if (p == 0) { stageA(kk2, bnext, 0); stageA(kk2, bnext, 1); }
        if (p == 1) { stageA(kk2, bnext, 2); stageA(kk2, bnext, 3); }
        if (p == 2) { stageB(kk2, bnext, 0); stageB(kk2, bnext, 1); }
      }
      asm volatile("s_waitcnt lgkmcnt(0)" ::: "memory");
      __builtin_amdgcn_s_setprio(1);
#pragma unroll
      for (int di = 0; di < 2; di++)
#pragma unroll
        for (int j = 0; j < 2; j++)
#pragma unroll
          for (int ks = 0; ks < 2; ks++)
            acc[p * 2 + di][j] =
                __builtin_amdgcn_mfma_f32_16x16x32_bf16(af[di][ks], bfr[j][ks],
                                                        acc[p * 2 + di][j], 0, 0, 0);
      __builtin_amdgcn_s_setprio(0);
      __builtin_amdgcn_s_barrier();
    }
  }

  const float* res = RES ? (resv + (size_t)z * sR) : nullptr;
  char* Cb = (char*)Cv + (size_t)z * sC * (OUT_BF16 ? 2 : 4);
#pragma unroll
  for (int i = 0; i < 8; i++) {
#pragma unroll
    for (int jj = 0; jj < 4; jj++) {
      int row = m0 + wr * 128 + i * 16 + g * 4 + jj;
#pragma unroll
      for (int j = 0; j < 2; j++) {
        int col = n0 + wc * 32 + j * 16 + l15;
        float v = acc[i][j][jj];
        if (BIAS_MODE == 1) v += bias[col];
        if (BIAS_MODE == 2) v += bias[row];
        if (RES) v += res[(size_t)row * N + col];
        if (OUT_BF16) ((unsigned short*)Cb)[(size_t)row * N + col] = f2bf(v);
        else          ((float*)Cb)[(size_t)row * N + col] = v;
      }
    }
  }
}

// ---------------- streaming softmax, in place on S bf16 [32768][1024] ----------
__global__ __launch_bounds__(256, 8) void k_softmax(unsigned short* __restrict__ S) {
  const int lane = threadIdx.x & 63;
  const int w = threadIdx.x >> 6;
  const float scale = 0.044194173824159216f;  // 512^-0.5
  for (int r = blockIdx.x * 4 + w; r < 32768; r += gridDim.x * 4) {
    unsigned short* p = S + (size_t)r * 1024 + lane * 16;
    short8 a = *(const short8*)p;
    short8 b = *(const short8*)(p + 8);
    float v[16];
#pragma unroll
    for (int i = 0; i < 8; i++) v[i] = bf2f((unsigned short)a[i]) * scale;
#pragma unroll
    for (int i = 0; i < 8; i++) v[8 + i] = bf2f((unsigned short)b[i]) * scale;
    float m = v[0];
#pragma unroll
    for (int i = 1; i < 16; i++) m = fmaxf(m, v[i]);
#pragma unroll
    for (int d = 1; d < 64; d <<= 1) m = fmaxf(m, __shfl_xor(m, d, 64));
    float s = 0.f;
#pragma unroll
    for (int i = 0; i < 16; i++) { v[i] = __expf(v[i] - m); s += v[i]; }
#pragma unroll
    for (int d = 1; d < 64; d <<= 1) s += __shfl_xor(s, d, 64);
    float inv = 1.0f / s;
    unsigned short tmp[16] __attribute__((aligned(16)));
#pragma unroll
    for (int i = 0; i < 16; i++) tmp[i] = f2bf(v[i] * inv);
    *(i32x4*)p = *(const i32x4*)tmp;
    *(i32x4*)(p + 8) = *(const i32x4*)(tmp + 8);
  }
}

// ---------------- launch ----------------
extern "C" void kernel_launch(void* const* d_in, const int* in_sizes, int n_in,
                              void* d_out, int out_size, void* d_ws, size_t ws_size,
                              hipStream_t stream) {
  (void)in_sizes; (void)n_in; (void)out_size; (void)ws_size;
  const float* x   = (const float*)d_in[0];
  const float* ctx = (const float*)d_in[1];
  const float* Wq  = (const float*)d_in[2];
  const float* bq  = (const float*)d_in[3];
  const float* Wk  = (const float*)d_in[4];
  const float* bk  = (const float*)d_in[5];
  const float* Wv  = (const float*)d_in[6];
  const float* bv  = (const float*)d_in[7];
  const float* Wo  = (const float*)d_in[8];
  const float* bo  = (const float*)d_in[9];
  float* out = (float*)d_out;

  char* ws = (char*)d_ws;
  unsigned short* qb   = (unsigned short*)(ws);              // 33,554,432
  unsigned short* kbuf = (unsigned short*)(ws + 33554432);   //  8,388,608
  unsigned short* vT   = (unsigned short*)(ws + 41943040);   //  8,388,608
  unsigned short* ctxb = (unsigned short*)(ws + 50331648);   // 33,554,432
  unsigned short* WqT  = (unsigned short*)(ws + 83886080);   //    524,288
  unsigned short* WkT  = (unsigned short*)(ws + 84410368);   //    786,432
  unsigned short* WvT  = (unsigned short*)(ws + 85196800);   //    786,432
  unsigned short* WoT  = (unsigned short*)(ws + 85983232);   //    524,288 -> 86,507,520
  // S overlays xb+cb (both dead by S-GEMM time)
  unsigned short* Sbuf = (unsigned short*)(ws + 86507520);   // 67,108,864 -> 153,616,384
  unsigned short* xb   = (unsigned short*)(ws + 86507520);   // 33,554,432
  unsigned short* cb   = (unsigned short*)(ws + 120061952);  // 12,582,912

  dim3 tb(32, 8);
  k_transpose<<<dim3(16, 16), tb, 0, stream>>>(Wq, WqT, 512, 512);
  k_transpose<<<dim3(24, 16), tb, 0, stream>>>(Wk, WkT, 768, 512);
  k_transpose<<<dim3(24, 16), tb, 0, stream>>>(Wv, WvT, 768, 512);
  k_transpose<<<dim3(16, 16), tb, 0, stream>>>(Wo, WoT, 512, 512);

  k_cast<<<dim3(2048), 256, 0, stream>>>(x,   xb, 2097152);
  k_cast<<<dim3(2048), 256, 0, stream>>>(ctx, cb,  786432);

  // q = x @ Wq + bq -> bf16 [32768][512]
  k_gemm2<1, false, true><<<dim3(128, 4, 1), 512, 0, stream>>>(
      xb, WqT, bq, nullptr, qb, 32768, 512, 512, 0, 0, 0, 0);
  // k = ctx @ Wk + bk -> bf16 [8192][512]
  k_gemm<1, false, true><<<dim3(64, 4, 1), 256, 0, stream>>>(
      cb, WkT, bk, nullptr, kbuf, 8192, 512, 768, 0, 0, 0, 0);
  // vT[b] = (ctx[b] @ Wv + bv)^T -> bf16 [8][512][1024]
  k_gemm<2, false, true><<<dim3(4, 8, 8), 256, 0, stream>>>(
      WvT, cb, bv, nullptr, vT, 512, 1024, 768, 0, (long)1024 * 768, (long)512 * 1024, 0);
  // S[b] = q[b] @ k[b]^T -> bf16 [8][4096][1024]  (scale folded into softmax)
  k_gemm2<0, false, true><<<dim3(16, 8, 8), 512, 0, stream>>>(
      qb, kbuf, nullptr, nullptr, Sbuf, 4096, 1024, 512,
      (long)4096 * 512, (long)1024 * 512, (long)4096 * 1024, 0);
  // P^ = softmax(S * scale), in place
  k_softmax<<<dim3(4096), 256, 0, stream>>>(Sbuf);
  // ctx_out[b] = P^[b] @ vT[b]^T -> bf16 [8][4096][512]
  k_gemm2<0, false, true><<<dim3(16, 4, 8), 512, 0, stream>>>(
      Sbuf, vT, nullptr, nullptr, ctxb, 4096, 512, 1024,
      (long)4096 * 1024, (long)512 * 1024, (long)4096 * 512, 0);
  // out = ctx_out @ Wo + bo + x -> f32
  k_gemm2<1, true, false><<<dim3(128, 4, 1), 512, 0, stream>>>(
      ctxb, WoT, bo, x, out, 32768, 512, 512, 0, 0, 0, 0);
}

// Round 6
// 237.220 us; speedup vs baseline: 1.1018x; 1.0463x over previous
//
#include <hip/hip_runtime.h>

typedef __attribute__((ext_vector_type(8))) short short8;
typedef __attribute__((ext_vector_type(4))) float f32x4;
typedef __attribute__((ext_vector_type(4))) int i32x4;

#define NSEQ 4096
#define MSEQ 1024
#define HID  512
#define CTXD 768

static __device__ __forceinline__ unsigned short f2bf(float f) {
  union { float f; unsigned u; } v; v.f = f;
  return (unsigned short)((v.u + 0x7fffu + ((v.u >> 16) & 1u)) >> 16);
}

static __device__ __forceinline__ void gld16(const void* g, void* l) {
  __builtin_amdgcn_global_load_lds((const __attribute__((address_space(1))) void*)g,
                                   (__attribute__((address_space(3))) void*)l, 16, 0, 0);
}
static __device__ __forceinline__ void gld4(const void* g, void* l) {
  __builtin_amdgcn_global_load_lds((const __attribute__((address_space(1))) void*)g,
                                   (__attribute__((address_space(3))) void*)l, 4, 0, 0);
}

// ---------------- weight transpose: W[K][N] f32 -> WT[N][K] bf16 ----------------
__global__ void k_transpose(const float* __restrict__ W, unsigned short* __restrict__ WT,
                            int K, int N) {
  __shared__ float tile[32][33];
  int k0 = blockIdx.x * 32, n0 = blockIdx.y * 32;
  int tx = threadIdx.x, ty = threadIdx.y;
#pragma unroll
  for (int i = 0; i < 32; i += 8)
    tile[ty + i][tx] = W[(size_t)(k0 + ty + i) * N + n0 + tx];
  __syncthreads();
#pragma unroll
  for (int i = 0; i < 32; i += 8)
    WT[(size_t)(n0 + ty + i) * K + k0 + tx] = f2bf(tile[tx][ty + i]);
}

// ---------------- f32 -> bf16 cast, vectorized ----------------
__global__ void k_cast(const float* __restrict__ in, unsigned short* __restrict__ out, int n8) {
  int i = blockIdx.x * blockDim.x + threadIdx.x;
  int stride = gridDim.x * blockDim.x;
  for (; i < n8; i += stride) {
    f32x4 v0 = *(const f32x4*)(in + (size_t)i * 8);
    f32x4 v1 = *(const f32x4*)(in + (size_t)i * 8 + 4);
    unsigned short tmp[8] __attribute__((aligned(16)));
    tmp[0] = f2bf(v0[0]); tmp[1] = f2bf(v0[1]); tmp[2] = f2bf(v0[2]); tmp[3] = f2bf(v0[3]);
    tmp[4] = f2bf(v1[0]); tmp[5] = f2bf(v1[1]); tmp[6] = f2bf(v1[2]); tmp[7] = f2bf(v1[3]);
    *(i32x4*)(out + (size_t)i * 8) = *(const i32x4*)tmp;
  }
}

// ---------------- GEMM 128x128 (R2-proven): C = A[M][K] * BT[N][K]^T ------------
template<int BIAS_MODE, bool RES, bool OUT_BF16>
__global__ __launch_bounds__(256, 2) void k_gemm(
    const unsigned short* __restrict__ A, const unsigned short* __restrict__ B,
    const float* __restrict__ bias, const float* __restrict__ resv,
    void* __restrict__ Cv, int M, int N, int K,
    long sA, long sB, long sC, long sR) {
  __shared__ __align__(16) char lds[65536];
  const int t = threadIdx.x, lane = t & 63, wid = t >> 6;
  const int wr = wid >> 1, wc = wid & 1;
  const int m0 = blockIdx.x * 128, n0 = blockIdx.y * 128, z = blockIdx.z;
  const unsigned short* Ab = A + (size_t)z * sA;
  const unsigned short* Bb = B + (size_t)z * sB;

  const f32x4 fz = {0.f, 0.f, 0.f, 0.f};
  f32x4 acc[4][4];
#pragma unroll
  for (int i = 0; i < 4; i++)
#pragma unroll
    for (int j = 0; j < 4; j++) acc[i][j] = fz;

  const int srow = t >> 3;      // 0..31
  const int schunk = t & 7;

  auto stage = [&](int kk, int buf) {
    const char* a8 = (const char*)Ab;
    const char* b8 = (const char*)Bb;
#pragma unroll
    for (int i = 0; i < 4; i++) {
      int row = i * 32 + srow;
      gld16(a8 + ((size_t)(m0 + row) * K + kk) * 2 + ((schunk ^ (row & 7)) << 4),
            lds + buf * 32768 + i * 4096 + wid * 1024);
    }
#pragma unroll
    for (int i = 0; i < 4; i++) {
      int row = i * 32 + srow;
      gld16(b8 + ((size_t)(n0 + row) * K + kk) * 2 + ((schunk ^ (row & 7)) << 4),
            lds + buf * 32768 + 16384 + i * 4096 + wid * 1024);
    }
  };

  stage(0, 0);
  int buf = 0;
  for (int kk = 0; kk < K; kk += 64) {
    if (kk + 64 < K) {
      stage(kk + 64, buf ^ 1);
      asm volatile("s_waitcnt vmcnt(8)" ::: "memory");
    } else {
      asm volatile("s_waitcnt vmcnt(0)" ::: "memory");
    }
    __builtin_amdgcn_s_barrier();
    const char* As = lds + buf * 32768;
    const char* Bs = As + 16384;
#pragma unroll
    for (int ks = 0; ks < 2; ks++) {
      short8 af[4], bfr[4];
#pragma unroll
      for (int i = 0; i < 4; i++) {
        int r = wr * 64 + i * 16 + (lane & 15);
        af[i] = *(const short8*)(As + r * 128 +
                 (((unsigned)(ks * 64 + (lane >> 4) * 16)) ^ ((unsigned)(r & 7) << 4)));
      }
#pragma unroll
      for (int i = 0; i < 4; i++) {
        int r = wc * 64 + i * 16 + (lane & 15);
        bfr[i] = *(const short8*)(Bs + r * 128 +
                 (((unsigned)(ks * 64 + (lane >> 4) * 16)) ^ ((unsigned)(r & 7) << 4)));
      }
#pragma unroll
      for (int i = 0; i < 4; i++)
#pragma unroll
        for (int j = 0; j < 4; j++)
          acc[i][j] = __builtin_amdgcn_mfma_f32_16x16x32_bf16(af[i], bfr[j], acc[i][j], 0, 0, 0);
    }
    asm volatile("s_waitcnt lgkmcnt(0)" ::: "memory");
    __builtin_amdgcn_s_barrier();
    buf ^= 1;
  }

  const float* res = RES ? (resv + (size_t)z * sR) : nullptr;
  char* Cb = (char*)Cv + (size_t)z * sC * (OUT_BF16 ? 2 : 4);
#pragma unroll
  for (int i = 0; i < 4; i++) {
#pragma unroll
    for (int jj = 0; jj < 4; jj++) {
      int row = m0 + wr * 64 + i * 16 + (lane >> 4) * 4 + jj;
#pragma unroll
      for (int j = 0; j < 4; j++) {
        int col = n0 + wc * 64 + j * 16 + (lane & 15);
        float v = acc[i][j][jj];
        if (BIAS_MODE == 1) v += bias[col];
        if (BIAS_MODE == 2) v += bias[row];
        if (RES) v += res[(size_t)row * N + col];
        if (OUT_BF16) ((unsigned short*)Cb)[(size_t)row * N + col] = f2bf(v);
        else          ((float*)Cb)[(size_t)row * N + col] = v;
      }
    }
  }
}

// ---------------- GEMM 256x256, BK=32, 8 waves (2x4), 3-buffer ring -------------
// Per-wave output 128x64: 12 ds_read_b128 per 32 MFMA (0.375 KB/MFMA).
// LDS rows are 64B (BK=32); two rows packed per 128B line with XOR swizzle
// (line&7)<<4 applied on BOTH the read address and the (inverse-mapped)
// global_load_lds source. Ring of 3 buffers, prefetch distance 2, boundary
// vmcnt(4) never drains mid-loop.
template<int BIAS_MODE, bool RES, bool OUT_BF16>
__global__ __launch_bounds__(512, 1) void k_gemm3(
    const unsigned short* __restrict__ A, const unsigned short* __restrict__ B,
    const float* __restrict__ bias, const float* __restrict__ resv,
    void* __restrict__ Cv, int M, int N, int K,
    long sA, long sB, long sC, long sR) {
  __shared__ __align__(16) char lds[98304];   // 3 x (A 16K + B 16K)
  const int t = threadIdx.x, lane = t & 63, wid = t >> 6;
  const int wr = wid >> 2, wc = wid & 3;
  const int l15 = lane & 15, g = lane >> 4;
  const int m0 = blockIdx.x * 256, n0 = blockIdx.y * 256, z = blockIdx.z;
  const unsigned short* Ab = A + (size_t)z * sA;
  const unsigned short* Bb = B + (size_t)z * sB;

  const f32x4 fz = {0.f, 0.f, 0.f, 0.f};
  f32x4 acc[8][4];
#pragma unroll
  for (int i = 0; i < 8; i++)
#pragma unroll
    for (int j = 0; j < 4; j++) acc[i][j] = fz;

  // per-lane inverse map for staging: LDS byte p -> logical (row, colbyte)
  int rS[2], cS[2];
#pragma unroll
  for (int u = 0; u < 2; u++) {
    int p = u * 8192 + wid * 1024 + lane * 16;
    int L = p >> 7;
    int q = (p & 127) ^ ((L & 7) << 4);
    rS[u] = 2 * L + (q >> 6);
    cS[u] = q & 63;
  }

  auto stageA = [&](int kk, int buf, int u) {
    gld16((const char*)Ab + ((size_t)(m0 + rS[u]) * K + kk) * 2 + cS[u],
          lds + buf * 32768 + u * 8192 + wid * 1024);
  };
  auto stageB = [&](int kk, int buf, int u) {
    gld16((const char*)Bb + ((size_t)(n0 + rS[u]) * K + kk) * 2 + cS[u],
          lds + buf * 32768 + 16384 + u * 8192 + wid * 1024);
  };

  // read-address helper: logical (r, g) -> LDS byte offset within region
  auto ldso = [&](int r, int gg) -> unsigned {
    unsigned L = (unsigned)(r >> 1);
    return L * 128 + ((((unsigned)(r & 1)) * 64 + (unsigned)gg * 16) ^ ((L & 7) << 4));
  };

  const int NT = K >> 5;
  // prologue: tiles 0 and 1
#pragma unroll
  for (int u = 0; u < 2; u++) { stageA(0, 0, u); }
#pragma unroll
  for (int u = 0; u < 2; u++) { stageB(0, 0, u); }
#pragma unroll
  for (int u = 0; u < 2; u++) { stageA(32, 1, u); }
#pragma unroll
  for (int u = 0; u < 2; u++) { stageB(32, 1, u); }

  for (int tt = 0; tt < NT; tt++) {
    if (tt + 1 < NT) { asm volatile("s_waitcnt vmcnt(4)" ::: "memory"); }
    else             { asm volatile("s_waitcnt vmcnt(0)" ::: "memory"); }
    __builtin_amdgcn_s_barrier();
    const char* As = lds + (tt % 3) * 32768;
    const char* Bs = As + 16384;
    const int kk2 = (tt + 2) << 5;
    const bool st = kk2 < K;
    const int bn = (tt + 2) % 3;

    short8 bfr[4];
#pragma unroll
    for (int p = 0; p < 2; p++) {
      short8 af[4];
#pragma unroll
      for (int fi = 0; fi < 4; fi++) {
        int r = wr * 128 + (p * 4 + fi) * 16 + l15;
        af[fi] = *(const short8*)(As + ldso(r, g));
      }
      if (p == 0) {
#pragma unroll
        for (int fj = 0; fj < 4; fj++) {
          int r = wc * 64 + fj * 16 + l15;
          bfr[fj] = *(const short8*)(Bs + ldso(r, g));
        }
        if (st) { stageA(kk2, bn, 0); stageA(kk2, bn, 1); }
      } else {
        if (st) { stageB(kk2, bn, 0); stageB(kk2, bn, 1); }
      }
      asm volatile("s_waitcnt lgkmcnt(0)" ::: "memory");
      __builtin_amdgcn_s_setprio(1);
#pragma unroll
      for (int fi = 0; fi < 4; fi++)
#pragma unroll
        for (int fj = 0; fj < 4; fj++)
          acc[p * 4 + fi][fj] =
              __builtin_amdgcn_mfma_f32_16x16x32_bf16(af[fi], bfr[fj], acc[p * 4 + fi][fj], 0, 0, 0);
      __builtin_amdgcn_s_setprio(0);
      __builtin_amdgcn_s_barrier();
    }
  }

  const float* res = RES ? (resv + (size_t)z * sR) : nullptr;
  char* Cb = (char*)Cv + (size_t)z * sC * (OUT_BF16 ? 2 : 4);
#pragma unroll
  for (int i = 0; i < 8; i++) {
#pragma unroll
    for (int jj = 0; jj < 4; jj++) {
      int row = m0 + wr * 128 + i * 16 + g * 4 + jj;
#pragma unroll
      for (int j = 0; j < 4; j++) {
        int col = n0 + wc * 64 + j * 16 + l15;
        float v = acc[i][j][jj];
        if (BIAS_MODE == 1) v += bias[col];
        if (BIAS_MODE == 2) v += bias[row];
        if (RES) v += res[(size_t)row * N + col];
        if (OUT_BF16) ((unsigned short*)Cb)[(size_t)row * N + col] = f2bf(v);
        else          ((float*)Cb)[(size_t)row * N + col] = v;
      }
    }
  }
}

// ---------------- QK^T + softmax -> normalized P^ (bf16), coalesced store -------
// R2-proven compute: 64 q-rows x full M=1024 per block, 8 waves, S in regs.
// New epilogue: P^ -> swizzled LDS [64][2048B] (dead K/Q region) -> 1KB/inst
// coalesced global stores.
__global__ __launch_bounds__(512, 1) void k_qks(
    const unsigned short* __restrict__ qb,   // [B*4096][512] bf16
    const unsigned short* __restrict__ kb,   // [B*1024][512] bf16
    unsigned short* __restrict__ phat) {     // [B][4096][1024] bf16 (normalized)
  __shared__ __align__(16) char lds[143616];
  char* Kb0 = lds;                         // [2][65536]
  char* Qb0 = lds + 131072;                // [2][4096]
  char* Ps  = lds;                         // [64][2048B] swizzled (epilogue)
  float* pmax = (float*)(lds + 139264);    // [8][64]
  float* psum = (float*)(lds + 141312);    // [8][64]
  float* gbuf = (float*)(lds + 143360);    // [64]

  const int t = threadIdx.x, lane = t & 63, w = t >> 6;
  const int g = lane >> 4, l15 = lane & 15;
  const int bid = blockIdx.x;
  const int b = bid & 7;                   // batch -> XCD affinity
  const int n0 = (bid >> 3) * 64;
  const char* qbase = (const char*)(qb + ((size_t)b * NSEQ + n0) * HID);
  const char* kbase = (const char*)(kb + (size_t)b * MSEQ * HID);

  auto stage = [&](int ks2, int buf) {
#pragma unroll
    for (int i = 0; i < 8; i++) {
      int row = i * 128 + (t >> 2);
      int c = t & 3;
      gld16(kbase + ((size_t)row * HID + ks2 * 32) * 2 + ((c ^ ((row >> 1) & 3)) << 4),
            Kb0 + buf * 65536 + i * 8192 + w * 1024);
    }
#pragma unroll
    for (int j = 0; j < 2; j++) {
      int row = j * 32 + (t >> 4);
      int o = (t & 15) * 4;
      gld4(qbase + ((size_t)row * HID + ks2 * 32) * 2 +
               ((((o >> 4) ^ ((row >> 1) & 3)) << 4) | (o & 15)),
           Qb0 + buf * 4096 + j * 2048 + w * 256);
    }
  };

  const f32x4 fz = {0.f, 0.f, 0.f, 0.f};
  f32x4 s[4][8];
#pragma unroll
  for (int qf = 0; qf < 4; qf++)
#pragma unroll
    for (int mf = 0; mf < 8; mf++) s[qf][mf] = fz;

  stage(0, 0);
  int buf = 0;
  for (int ks2 = 0; ks2 < 16; ks2++) {
    if (ks2 < 15) {
      stage(ks2 + 1, buf ^ 1);
      asm volatile("s_waitcnt vmcnt(10)" ::: "memory");
    } else {
      asm volatile("s_waitcnt vmcnt(0)" ::: "memory");
    }
    __builtin_amdgcn_s_barrier();
    const char* Kc = Kb0 + buf * 65536;
    const char* Qc = Qb0 + buf * 4096;
    short8 aq[4], bk[8];
#pragma unroll
    for (int qf = 0; qf < 4; qf++) {
      int q = qf * 16 + l15;
      aq[qf] = *(const short8*)(Qc + q * 64 + ((g * 16) ^ (((q >> 1) & 3) << 4)));
    }
#pragma unroll
    for (int mf = 0; mf < 8; mf++) {
      int m = w * 128 + mf * 16 + l15;
      bk[mf] = *(const short8*)(Kc + m * 64 + ((g * 16) ^ (((m >> 1) & 3) << 4)));
    }
#pragma unroll
    for (int qf = 0; qf < 4; qf++)
#pragma unroll
      for (int mf = 0; mf < 8; mf++)
        s[qf][mf] = __builtin_amdgcn_mfma_f32_16x16x32_bf16(aq[qf], bk[mf], s[qf][mf], 0, 0, 0);
    asm volatile("s_waitcnt lgkmcnt(0)" ::: "memory");
    __builtin_amdgcn_s_barrier();
    buf ^= 1;
  }

  // ---- softmax (exact, full row) ----
  const float scale = 0.044194173824159216f;  // 512^-0.5
#pragma unroll
  for (int qf = 0; qf < 4; qf++)
#pragma unroll
    for (int mf = 0; mf < 8; mf++)
#pragma unroll
      for (int jj = 0; jj < 4; jj++) s[qf][mf][jj] *= scale;

  float rmax[4][4];
#pragma unroll
  for (int qf = 0; qf < 4; qf++)
#pragma unroll
    for (int jj = 0; jj < 4; jj++) {
      float m = s[qf][0][jj];
#pragma unroll
      for (int mf = 1; mf < 8; mf++) m = fmaxf(m, s[qf][mf][jj]);
      rmax[qf][jj] = m;
    }
#pragma unroll
  for (int d = 1; d < 16; d <<= 1)
#pragma unroll
    for (int qf = 0; qf < 4; qf++)
#pragma unroll
      for (int jj = 0; jj < 4; jj++)
        rmax[qf][jj] = fmaxf(rmax[qf][jj], __shfl_xor(rmax[qf][jj], d, 64));
  if (l15 == 0) {
#pragma unroll
    for (int qf = 0; qf < 4; qf++)
#pragma unroll
      for (int jj = 0; jj < 4; jj++)
        pmax[w * 64 + qf * 16 + g * 4 + jj] = rmax[qf][jj];
  }
  __syncthreads();
  if (t < 64) {
    float m = pmax[t];
#pragma unroll
    for (int ww = 1; ww < 8; ww++) m = fmaxf(m, pmax[ww * 64 + t]);
    gbuf[t] = m;
  }
  __syncthreads();
  float fm[4][4], rs[4][4];
#pragma unroll
  for (int qf = 0; qf < 4; qf++)
#pragma unroll
    for (int jj = 0; jj < 4; jj++) {
      fm[qf][jj] = gbuf[qf * 16 + g * 4 + jj];
      rs[qf][jj] = 0.f;
    }
#pragma unroll
  for (int qf = 0; qf < 4; qf++)
#pragma unroll
    for (int mf = 0; mf < 8; mf++)
#pragma unroll
      for (int jj = 0; jj < 4; jj++) {
        float p = __expf(s[qf][mf][jj] - fm[qf][jj]);
        s[qf][mf][jj] = p;
        rs[qf][jj] += p;
      }
#pragma unroll
  for (int d = 1; d < 16; d <<= 1)
#pragma unroll
    for (int qf = 0; qf < 4; qf++)
#pragma unroll
      for (int jj = 0; jj < 4; jj++)
        rs[qf][jj] += __shfl_xor(rs[qf][jj], d, 64);
  __syncthreads();
  if (l15 == 0) {
#pragma unroll
    for (int qf = 0; qf < 4; qf++)
#pragma unroll
      for (int jj = 0; jj < 4; jj++)
        psum[w * 64 + qf * 16 + g * 4 + jj] = rs[qf][jj];
  }
  __syncthreads();
  if (t < 64) {
    float ssum = psum[t];
#pragma unroll
    for (int ww = 1; ww < 8; ww++) ssum += psum[ww * 64 + t];
    gbuf[t] = 1.0f / ssum;
  }
  __syncthreads();   // gbuf ready; K/Q buffers dead -> Ps may overwrite them

  // ---- P^ (normalized, bf16) -> LDS [64][2048B], XOR swizzle (row&15)<<4 ----
#pragma unroll
  for (int qf = 0; qf < 4; qf++)
#pragma unroll
    for (int jj = 0; jj < 4; jj++) {
      int row = qf * 16 + g * 4 + jj;
      float fi = gbuf[row];
      char* pr = Ps + row * 2048;
      unsigned cr = (unsigned)(row & 15) << 4;
#pragma unroll
      for (int mf = 0; mf < 8; mf++) {
        int col = w * 128 + mf * 16 + l15;
        *(unsigned short*)(pr + (((unsigned)(col * 2)) ^ cr)) = f2bf(s[qf][mf][jj] * fi);
      }
    }
  __syncthreads();

  // ---- coalesced store: wave w -> rows [w*8, w*8+8), 1KB per instruction ----
  {
    unsigned short* pb = phat + (size_t)b * NSEQ * MSEQ;
#pragma unroll
    for (int r8 = 0; r8 < 8; r8++) {
      int row = w * 8 + r8;
      unsigned cr = (unsigned)(row & 15) << 4;
      char* src = Ps + row * 2048;
      char* dst = (char*)(pb + (size_t)(n0 + row) * MSEQ);
#pragma unroll
      for (int half = 0; half < 2; half++) {
        unsigned q = (unsigned)(half * 1024 + lane * 16);
        i32x4 v = *(const i32x4*)(src + (q ^ cr));
        *(i32x4*)(dst + q) = v;
      }
    }
  }
}

// ---------------- launch ----------------
extern "C" void kernel_launch(void* const* d_in, const int* in_sizes, int n_in,
                              void* d_out, int out_size, void* d_ws, size_t ws_size,
                              hipStream_t stream) {
  (void)in_sizes; (void)n_in; (void)out_size; (void)ws_size;
  const float* x   = (const float*)d_in[0];
  const float* ctx = (const float*)d_in[1];
  const float* Wq  = (const float*)d_in[2];
  const float* bq  = (const float*)d_in[3];
  const float* Wk  = (const float*)d_in[4];
  const float* bk  = (const float*)d_in[5];
  const float* Wv  = (const float*)d_in[6];
  const float* bv  = (const float*)d_in[7];
  const float* Wo  = (const float*)d_in[8];
  const float* bo  = (const float*)d_in[9];
  float* out = (float*)d_out;

  char* ws = (char*)d_ws;
  unsigned short* qb   = (unsigned short*)(ws);              // 33,554,432
  unsigned short* kbuf = (unsigned short*)(ws + 33554432);   //  8,388,608
  unsigned short* vT   = (unsigned short*)(ws + 41943040);   //  8,388,608
  unsigned short* ctxb = (unsigned short*)(ws + 50331648);   // 33,554,432
  unsigned short* WqT  = (unsigned short*)(ws + 83886080);   //    524,288
  unsigned short* WkT  = (unsigned short*)(ws + 84410368);   //    786,432
  unsigned short* WvT  = (unsigned short*)(ws + 85196800);   //    786,432
  unsigned short* WoT  = (unsigned short*)(ws + 85983232);   //    524,288 -> 86,507,520
  // phat overlays xb+cb (both dead by k_qks time)
  unsigned short* phat = (unsigned short*)(ws + 86507520);   // 67,108,864 -> 153,616,384
  unsigned short* xb   = (unsigned short*)(ws + 86507520);   // 33,554,432
  unsigned short* cb   = (unsigned short*)(ws + 120061952);  // 12,582,912

  dim3 tb(32, 8);
  k_transpose<<<dim3(16, 16), tb, 0, stream>>>(Wq, WqT, 512, 512);
  k_transpose<<<dim3(24, 16), tb, 0, stream>>>(Wk, WkT, 768, 512);
  k_transpose<<<dim3(24, 16), tb, 0, stream>>>(Wv, WvT, 768, 512);
  k_transpose<<<dim3(16, 16), tb, 0, stream>>>(Wo, WoT, 512, 512);

  k_cast<<<dim3(2048), 256, 0, stream>>>(x,   xb, 2097152);
  k_cast<<<dim3(2048), 256, 0, stream>>>(ctx, cb,  786432);

  // q = x @ Wq + bq -> bf16 [32768][512]
  k_gemm3<1, false, true><<<dim3(128, 2, 1), 512, 0, stream>>>(
      xb, WqT, bq, nullptr, qb, 32768, 512, 512, 0, 0, 0, 0);
  // k = ctx @ Wk + bk -> bf16 [8192][512]
  k_gemm<1, false, true><<<dim3(64, 4, 1), 256, 0, stream>>>(
      cb, WkT, bk, nullptr, kbuf, 8192, 512, 768, 0, 0, 0, 0);
  // vT[b] = (ctx[b] @ Wv + bv)^T -> bf16 [8][512][1024]
  k_gemm<2, false, true><<<dim3(4, 8, 8), 256, 0, stream>>>(
      WvT, cb, bv, nullptr, vT, 512, 1024, 768, 0, (long)1024 * 768, (long)512 * 1024, 0);
  // P^ = softmax(q k^T * scale), normalized -> bf16 [8][4096][1024]
  k_qks<<<dim3(512), 512, 0, stream>>>(qb, kbuf, phat);
  // ctx_out[b] = P^[b] @ vT[b]^T -> bf16 [8][4096][512]
  k_gemm3<0, false, true><<<dim3(16, 2, 8), 512, 0, stream>>>(
      phat, vT, nullptr, nullptr, ctxb, 4096, 512, 1024,
      (long)4096 * 1024, (long)512 * 1024, (long)4096 * 512, 0);
  // out = ctx_out @ Wo + bo + x -> f32
  k_gemm3<1, true, false><<<dim3(128, 2, 1), 512, 0, stream>>>(
      ctxb, WoT, bo, x, out, 32768, 512, 512, 0, 0, 0, 0);
}